// Round 8
// baseline (2900.507 us; speedup 1.0000x reference)
//
#include <hip/hip_runtime.h>

typedef __attribute__((ext_vector_type(8))) short short8;
typedef __attribute__((ext_vector_type(4))) float f32x4;

#define ACT_P 23384064ul       /* padded: sum(HpWp)*256*4n */
#define WSTEP 589824           /* 9 tap * 32 ci8 * 256 co * 8 */

__device__ unsigned short g_actC[ACT_P];
__device__ unsigned short g_actA0[ACT_P];
__device__ unsigned short g_actB0[ACT_P];
__device__ unsigned short g_actA1[ACT_P];
__device__ unsigned short g_actB1[ACT_P];
__device__ unsigned short g_wc[4 * WSTEP];
__device__ unsigned short g_wr[4 * WSTEP];
__device__ unsigned short g_w1c[80 * 256];

__constant__ int      C_W[5]    = {128, 64, 32, 16, 8};
__constant__ int      C_WP[5]   = {130, 66, 34, 18, 10};
__constant__ int      C_HWP[5]  = {16900, 4356, 1156, 324, 100};
__constant__ int      C_LW[5]   = {7, 6, 5, 4, 3};
__constant__ int      C_LXT[5]  = {3, 2, 1, 0, 0};          // log2(W/16 x-tiles)
__constant__ int      C_PREF[5] = {0, 64, 80, 84, 85};      // tile prefix (86 total)
__constant__ int      C_HW[5]   = {16384, 4096, 1024, 256, 64};
__constant__ unsigned C_LOFFP[5]= {0u, 17305600u, 21766144u, 22949888u, 23281664u};
__constant__ unsigned C_CLSO[5] = {0u, 5242880u, 6553600u, 6881280u, 6963200u};
__constant__ unsigned C_REGO[5] = {6983680u, 7245824u, 7311360u, 7327744u, 7331840u};
__constant__ unsigned C_CENTO[5]= {7332864u, 7398400u, 7414784u, 7418880u, 7419904u};
__constant__ float    C_STRF[5] = {8.f, 16.f, 32.f, 64.f, 128.f};

static __device__ __forceinline__ unsigned short f2bf(float f) {
    unsigned u = __float_as_uint(f);
    unsigned r = (u + 0x7FFFu + ((u >> 16) & 1u)) >> 16;
    return (unsigned short)r;
}
static __device__ __forceinline__ float bf2f(unsigned short b) {
    return __uint_as_float(((unsigned)b) << 16);
}

// inline-asm global b128 loads with immediate offsets: cannot be deleted or
// re-scheduled by hipcc; one VALU-computed address serves 4 loads.
#define GLOAD0(dst, ptr) \
    asm volatile("global_load_dwordx4 %0, %1, off" : "=v"(dst) : "v"(ptr))
#define GLOAD_OFF(dst, ptr, imm) \
    asm volatile("global_load_dwordx4 %0, %1, off offset:" #imm : "=v"(dst) : "v"(ptr))

// ---------------------------------------------------------------------------
// weight convert: (4,256,256,3,3) fp32 -> [step][tap(9)][ci8(32)][co(256)][8] bf16
// ---------------------------------------------------------------------------
__global__ __launch_bounds__(256) void cvt_w3(
    const float* __restrict__ wc, const float* __restrict__ wr,
    unsigned short* __restrict__ oc, unsigned short* __restrict__ orr)
{
    const int co = blockIdx.x, sm = blockIdx.y, head = blockIdx.z;
    const int step = sm / 9, tap = sm - step * 9;
    const int ci = threadIdx.x;
    const float* w = head ? wr : wc;
    unsigned short* o = head ? orr : oc;
    o[(((size_t)sm * 32 + (ci >> 3)) * 256 + co) * 8 + (ci & 7)] =
        f2bf(w[(((size_t)step * 256 + co) * 256 + ci) * 9 + tap]);
}

__global__ __launch_bounds__(256) void cvt_w1(
    const float* __restrict__ w, unsigned short* __restrict__ o)
{
    for (int idx = threadIdx.x; idx < 80 * 256; idx += 256)
        o[idx] = f2bf(w[idx]);
}

// ---------------------------------------------------------------------------
// zero the 1-px halo border of every level/n of all 5 padded buffers
// ---------------------------------------------------------------------------
__global__ __launch_bounds__(256) void zero_halo(
    unsigned short* c, unsigned short* a0, unsigned short* b0,
    unsigned short* a1, unsigned short* b1)
{
    unsigned short* bufs[5] = {c, a0, b0, a1, b1};
    const int bid = blockIdx.x;
    const int buf = bid / 20, r = bid - buf * 20, lvl = r >> 2, n = r & 3;
    const int Wp = C_WP[lvl], Hp = Wp;
    unsigned short* base = bufs[buf] + C_LOFFP[lvl] + (size_t)n * C_HWP[lvl] * 256;
    const int hc = 2 * Wp + 2 * (Hp - 2);
    uint4 z; z.x = z.y = z.z = z.w = 0u;
    for (int idx = threadIdx.x; idx < hc * 32; idx += 256) {
        int pos = idx >> 5, q = idx & 31;
        int row, col;
        if (pos < 2 * Wp) { row = (pos >= Wp) ? (Hp - 1) : 0; col = (pos >= Wp) ? pos - Wp : pos; }
        else { int rem = pos - 2 * Wp; row = 1 + (rem >> 1); col = (rem & 1) ? (Wp - 1) : 0; }
        *(uint4*)(base + ((size_t)(row * Wp + col) << 8) + q * 8) = z;
    }
}

// ---------------------------------------------------------------------------
// input convert: fp32 NCHW -> bf16 padded NHWC.
// ---------------------------------------------------------------------------
__global__ __launch_bounds__(256) void cvt_in(
    const float* __restrict__ f0, const float* __restrict__ f1,
    const float* __restrict__ f2, const float* __restrict__ f3,
    const float* __restrict__ f4, unsigned short* __restrict__ dstC)
{
    const int lvl = blockIdx.y, n = blockIdx.z;
    const int HW = C_HW[lvl];
    const int p0 = blockIdx.x * 64;
    if (p0 >= HW) return;
    const int W = C_W[lvl], lw = C_LW[lvl], Wp = C_WP[lvl];
    const float* fp[5] = {f0, f1, f2, f3, f4};
    const float* src = fp[lvl] + (size_t)n * 256 * HW;
    unsigned short* dst = dstC + C_LOFFP[lvl] + (size_t)n * C_HWP[lvl] * 256;
    const int tid = threadIdx.x;
    __shared__ float ts[64][65];

    for (int cc = 0; cc < 256; cc += 64) {
        for (int idx = tid; idx < 64 * 64; idx += 256) {
            int ci = idx >> 6, p = idx & 63;
            ts[ci][p] = src[(size_t)(cc + ci) * HW + p0 + p];
        }
        __syncthreads();
        for (int idx = tid; idx < 64 * 64; idx += 256) {
            int p = idx >> 6, ci = idx & 63;
            int gp = p0 + p, y = gp >> lw, x = gp & (W - 1);
            dst[(size_t)((y + 1) * Wp + x + 1) * 256 + cc + ci] = f2bf(ts[ci][p]);
        }
        __syncthreads();
    }
}

// ---------------------------------------------------------------------------
// 3x3 conv + BN + ReLU, bf16 MFMA implicit GEMM.
// Block = 512 thr = 8 waves (4 coq x 2 xh): tile 256 co x 256 px (16y x 16x).
// Wave = 64 co x 128 px (16y x 8x), acc 4x8 f32x4 = 128 AGPR.
// r7 diagnosis: per-CU L2 WEIGHT FETCH is the binding limit (32KB/tap/CU
// ~550cyc vs 155cyc of MFMA).  This tile doubles MFMA per weight byte
// (32 MFMA per 4 b128 loads/wave) and halves block count (86x8): weight L2
// traffic 3.2GB -> 1.6GB.  acc 4x8 is spill-safe here because LDS (87.5KB)
// forces 1 block/CU -> __launch_bounds__(512,1) = 512-reg budget
// (acc 128 AGPR + Af 64 + Bf 80 + addr ~= 320).
// Keep r7's asm depth-3 weight pipeline (global_load_dwordx4 + counted
// s_waitcnt vmcnt(12/8/4/0) + sched_barrier) that lifted MfmaUtil 35->42.
// Imm-offset loads: 1 address + offset:0/256/512/768 per tap (VALU cut).
// B halo tile (18y x 18x) streamed through ONE half-ci 87.5KB LDS buffer,
// overwritten between phases (barrier-stage-barrier).  lvl4 (8x8) pads into
// a 16x16 tile: staging clamps to the zeroed halo row/col, stores guarded.
// LDS layout [g(16)][x(18)][y(19 pad)] x 16B.
// grid: (86 packed tiles, 1, 8 = head*4+n).
// ---------------------------------------------------------------------------
__global__ __launch_bounds__(512, 1) void conv3x3_mfma(
    const unsigned short* __restrict__ src0, const unsigned short* __restrict__ src1,
    unsigned short* __restrict__ dst0, unsigned short* __restrict__ dst1,
    const unsigned short* __restrict__ wt0, const unsigned short* __restrict__ wt1,
    const float* __restrict__ sc0, const float* __restrict__ bi0,
    const float* __restrict__ sc1, const float* __restrict__ bi1)
{
    int tc = blockIdx.x;
    const int lvl = (tc >= 64) + (tc >= 80) + (tc >= 84) + (tc >= 85);
    tc -= C_PREF[lvl];
    const int head = blockIdx.z >> 2, n = blockIdx.z & 3;

    const int W = C_W[lvl], H = W, Wp = C_WP[lvl];
    const int lxt = C_LXT[lvl];
    const int tx = tc & ((1 << lxt) - 1), ty = tc >> lxt;
    const int x0 = tx * 16, y0 = ty * 16;

    const unsigned short* src = head ? src1 : src0;
    unsigned short*       dst = head ? dst1 : dst0;
    const unsigned short* wt  = head ? wt1 : wt0;
    const float* sc = head ? sc1 : sc0;
    const float* bi = head ? bi1 : bi0;
    const size_t actOff = (size_t)C_LOFFP[lvl] + (size_t)n * C_HWP[lvl] * 256;
    src += actOff; dst += actOff;

    const int tid = threadIdx.x;
    const int lane = tid & 63, wid = tid >> 6;
    const int l16 = lane & 15, quad = lane >> 4;
    const int coq = wid & 3, xh = wid >> 2;
    const int cow = coq * 64, jw = xh * 8;

    // LDS: [g(16)][x(18)][y(19)] x 16B = 87552 B (half-ci, reused both phases)
    __shared__ unsigned short B_s[16 * 18 * 19 * 8];
    char* Bb = (char*)B_s;

    // ---- staging addresses: 16 g-slices x 324 halo px = 5184 slots ----
    int goff[11], ldso[11];
#pragma unroll
    for (int it = 0; it < 11; it++) {
        int slot = tid + it * 512;
        if (slot > 5183) slot = 5183;
        int g = slot & 15, p = slot >> 4;       // p = y*18 + x, p < 324
        int y = (p * 57) >> 10;                 // /18 (exact for p<324)
        int x = p - y * 18;
        int gyp = y0 + y; if (gyp > Wp - 1) gyp = Wp - 1;   // lvl4 clamp (zero halo)
        int gxp = x0 + x; if (gxp > Wp - 1) gxp = Wp - 1;   // lvl4 clamp (zero halo)
        goff[it] = (((gyp * Wp) + gxp) << 8) + g * 8;
        ldso[it] = ((g * 18 + x) * 19 + y) * 16;
    }

    f32x4 acc[4][8];
#pragma unroll
    for (int mf = 0; mf < 4; mf++)
#pragma unroll
        for (int nf = 0; nf < 8; nf++) acc[mf][nf] = (f32x4){0.f, 0.f, 0.f, 0.f};

    // transient staging of one ci-half (cio = 0 or 128 ushorts), 2 rounds
    auto stage_half = [&](int cio) {
#pragma unroll
        for (int rnd = 0; rnd < 2; rnd++) {
            const int nb = rnd ? 5 : 6;
            uint4 tv[6];
#pragma unroll
            for (int it = 0; it < 6; it++)
                if (it < nb) tv[it] = *(const uint4*)(src + goff[rnd * 6 + it] + cio);
#pragma unroll
            for (int it = 0; it < 6; it++)
                if (it < nb) *(uint4*)(Bb + ldso[rnd * 6 + it]) = tv[it];
        }
    };

    // ---- stage half-0 (ci 0..127) ----
    stage_half(0);
    __syncthreads();

#pragma unroll
    for (int ph = 0; ph < 2; ph++) {
        if (ph == 1) {
            __syncthreads();   // all waves done reading half-0
            stage_half(128);   // overwrite with ci 128..255
            __syncthreads();   // half-1 visible
        }

        short8 Af[4][4];    // depth-3 in-flight + 1 in-use (asm-pinned)
        short8 Bf[2][10];   // double-buffered LDS fragments per (c4,kh)

        auto wBase = [&](int T) -> const unsigned short* {
            const int c4 = T / 9, tap = T - 9 * c4;
            const int c32 = ph * 4 + c4;
            return wt + (((tap * 32 + c32 * 4 + quad) * 256) + cow + l16) * 8;
        };
        auto issueA = [&](int T, short8* dA) {
            const unsigned short* p = wBase(T);
            GLOAD0(dA[0], p);
            GLOAD_OFF(dA[1], p, 256);
            GLOAD_OFF(dA[2], p, 512);
            GLOAD_OFF(dA[3], p, 768);
        };
        auto loadB = [&](int g, short8* dB) {    // g = c4*3 + kh, 0..11
            const int c4 = g / 3, kh = g - 3 * c4;
#pragma unroll
            for (int j = 0; j < 10; j++)
                dB[j] = *(const short8*)(Bb +
                    (((c4 * 4 + quad) * 18 + jw + j) * 19 + l16 + kh) * 16);
        };

        // prologue: issue taps 0..2 (12 loads in flight)
#pragma unroll
        for (int t = 0; t < 3; t++) issueA(t, Af[t]);
        loadB(0, Bf[0]);

#pragma unroll
        for (int T = 0; T < 36; T++) {
            const int g = T / 3, kw = T - g * 3;
            if (T + 3 < 36) issueA(T + 3, Af[(T + 3) & 3]);
            if (kw == 0 && g + 1 < 12) loadB(g + 1, Bf[(g + 1) & 1]);
            // counted waits: tap T's 4 loads (oldest) proven complete; up to
            // 3 taps (12 loads) stay in flight across the MFMA cluster.
            if (T + 3 < 36)      asm volatile("s_waitcnt vmcnt(12)" ::: "memory");
            else if (T + 2 < 36) asm volatile("s_waitcnt vmcnt(8)" ::: "memory");
            else if (T + 1 < 36) asm volatile("s_waitcnt vmcnt(4)" ::: "memory");
            else                 asm volatile("s_waitcnt vmcnt(0)" ::: "memory");
            __builtin_amdgcn_sched_barrier(0);
            const short8* Ac = Af[T & 3];
            const short8* Bc = Bf[g & 1];
#pragma unroll
            for (int nf = 0; nf < 8; nf++)
#pragma unroll
                for (int mf = 0; mf < 4; mf++)
                    acc[mf][nf] = __builtin_amdgcn_mfma_f32_16x16x32_bf16(
                        Ac[mf], Bc[nf + kw], acc[mf][nf], 0, 0, 0);
        }
    }

    // ---- epilogue: BN + ReLU + cvt bf16, padded NHWC store ----
    const int gy = y0 + l16;
    if (gy < H) {
#pragma unroll
        for (int mf = 0; mf < 4; mf++) {
            const int co4 = cow + mf * 16 + quad * 4;
            const f32x4 s4 = *(const f32x4*)(sc + co4);
            const f32x4 b4 = *(const f32x4*)(bi + co4);
#pragma unroll
            for (int nf = 0; nf < 8; nf++) {
                const int gx = x0 + jw + nf;
                if (gx < W) {
                    f32x4 v = acc[mf][nf];
                    ushort4 o;
                    o.x = f2bf(fmaxf(v[0] * s4[0] + b4[0], 0.f));
                    o.y = f2bf(fmaxf(v[1] * s4[1] + b4[1], 0.f));
                    o.z = f2bf(fmaxf(v[2] * s4[2] + b4[2], 0.f));
                    o.w = f2bf(fmaxf(v[3] * s4[3] + b4[3], 0.f));
                    *(ushort4*)(dst + ((size_t)((gy + 1) * Wp + gx + 1) * 256 + co4)) = o;
                }
            }
        }
    }
}

// ---------------------------------------------------------------------------
// final 1x1 cls: 256 -> 80 + bias, MFMA, fp32 NCHW out (padded NHWC input).
// ---------------------------------------------------------------------------
__global__ __launch_bounds__(256) void final_cls(
    const unsigned short* __restrict__ act, const unsigned short* __restrict__ w,
    const float* __restrict__ bias, float* __restrict__ out)
{
    const int lvl = blockIdx.y, n = blockIdx.z;
    const int HW = C_HW[lvl];
    const int p0 = blockIdx.x * 128;
    if (p0 >= HW) return;
    const int W = C_W[lvl], lw = C_LW[lvl], Wp = C_WP[lvl];

    const int tid = threadIdx.x;
    const int lane = tid & 63, wid = tid >> 6;
    const int l16 = lane & 15, quad = lane >> 4;

    const unsigned short* a = act + C_LOFFP[lvl] + (size_t)n * C_HWP[lvl] * 256;

    int px[2]; size_t aoff[2];
#pragma unroll
    for (int j = 0; j < 2; j++) {
        px[j] = p0 + wid * 32 + j * 16 + l16;
        int lpx = px[j] < HW ? px[j] : 0;
        int y = lpx >> lw, x = lpx & (W - 1);
        aoff[j] = (size_t)((y + 1) * Wp + x + 1) * 256;
    }

    f32x4 acc[5][2];
#pragma unroll
    for (int mf = 0; mf < 5; mf++) { acc[mf][0] = (f32x4){0,0,0,0}; acc[mf][1] = (f32x4){0,0,0,0}; }

    for (int cc = 0; cc < 256; cc += 32) {
        short8 b0 = *(const short8*)(a + aoff[0] + cc + quad * 8);
        short8 b1 = *(const short8*)(a + aoff[1] + cc + quad * 8);
#pragma unroll
        for (int mf = 0; mf < 5; mf++) {
            short8 av = *(const short8*)(w + (mf * 16 + l16) * 256 + cc + quad * 8);
            acc[mf][0] = __builtin_amdgcn_mfma_f32_16x16x32_bf16(av, b0, acc[mf][0], 0, 0, 0);
            acc[mf][1] = __builtin_amdgcn_mfma_f32_16x16x32_bf16(av, b1, acc[mf][1], 0, 0, 0);
        }
    }

    float* ob = out + C_CLSO[lvl] + (size_t)n * 80 * HW;
#pragma unroll
    for (int mf = 0; mf < 5; mf++) {
        const int co0 = mf * 16 + quad * 4;
#pragma unroll
        for (int j = 0; j < 2; j++) {
            if (px[j] < HW) {
#pragma unroll
                for (int r = 0; r < 4; r++)
                    ob[(size_t)(co0 + r) * HW + px[j]] = acc[mf][j][r] + bias[co0 + r];
            }
        }
    }
}

// ---------------------------------------------------------------------------
// final 1x1 reg: 256 -> 5 + bias; ch0 centerness, ch1..4 max(raw*stride,0).
// ---------------------------------------------------------------------------
__global__ __launch_bounds__(256) void final_reg(
    const unsigned short* __restrict__ act, const float* __restrict__ w,
    const float* __restrict__ bias, float* __restrict__ out)
{
    const int lvl = blockIdx.y, n = blockIdx.z;
    const int HW = C_HW[lvl];
    const int W = C_W[lvl], lw = C_LW[lvl], Wp = C_WP[lvl];
    const int tid = threadIdx.x;

    __shared__ float ws[5 * 256];
    for (int idx = tid; idx < 5 * 256; idx += 256) ws[idx] = w[idx];
    __syncthreads();

    const int px = blockIdx.x * 256 + tid;
    if (px >= HW) return;

    const int y = px >> lw, x = px & (W - 1);
    const unsigned short* a = act + C_LOFFP[lvl] + (size_t)n * C_HWP[lvl] * 256
                            + (size_t)((y + 1) * Wp + x + 1) * 256;
    float acc[5] = {0.f, 0.f, 0.f, 0.f, 0.f};

    for (int ci = 0; ci < 256; ci += 8) {
        ushort4 u0 = *(const ushort4*)(a + ci);
        ushort4 u1 = *(const ushort4*)(a + ci + 4);
        float xv[8] = {bf2f(u0.x), bf2f(u0.y), bf2f(u0.z), bf2f(u0.w),
                       bf2f(u1.x), bf2f(u1.y), bf2f(u1.z), bf2f(u1.w)};
#pragma unroll
        for (int j = 0; j < 5; j++) {
            const float* wj = &ws[j * 256 + ci];
#pragma unroll
            for (int k = 0; k < 8; k++) acc[j] = fmaf(xv[k], wj[k], acc[j]);
        }
    }

    const float strf = C_STRF[lvl];
    out[C_CENTO[lvl] + (size_t)n * HW + px] = acc[0] + bias[0];
    float* rb = out + C_REGO[lvl] + (size_t)n * 4 * HW;
#pragma unroll
    for (int j = 0; j < 4; j++)
        rb[(size_t)j * HW + px] = fmaxf((acc[j + 1] + bias[j + 1]) * strf, 0.f);
}

// ---------------------------------------------------------------------------
extern "C" void kernel_launch(void* const* d_in, const int* in_sizes, int n_in,
                              void* d_out, int out_size, void* d_ws, size_t ws_size,
                              hipStream_t stream)
{
    const float* cls_w  = (const float*)d_in[5];
    const float* cls_s  = (const float*)d_in[6];
    const float* cls_b  = (const float*)d_in[7];
    const float* cls_fw = (const float*)d_in[8];
    const float* cls_fb = (const float*)d_in[9];
    const float* reg_w  = (const float*)d_in[10];
    const float* reg_s  = (const float*)d_in[11];
    const float* reg_b  = (const float*)d_in[12];
    const float* reg_fw = (const float*)d_in[13];
    const float* reg_fb = (const float*)d_in[14];
    float* out = (float*)d_out;

    unsigned short *actC, *actA0, *actB0, *actA1, *actB1, *wc, *wr, *w1c;
    hipGetSymbolAddress((void**)&actC,  HIP_SYMBOL(g_actC));
    hipGetSymbolAddress((void**)&actA0, HIP_SYMBOL(g_actA0));
    hipGetSymbolAddress((void**)&actB0, HIP_SYMBOL(g_actB0));
    hipGetSymbolAddress((void**)&actA1, HIP_SYMBOL(g_actA1));
    hipGetSymbolAddress((void**)&actB1, HIP_SYMBOL(g_actB1));
    hipGetSymbolAddress((void**)&wc,    HIP_SYMBOL(g_wc));
    hipGetSymbolAddress((void**)&wr,    HIP_SYMBOL(g_wr));
    hipGetSymbolAddress((void**)&w1c,   HIP_SYMBOL(g_w1c));

    cvt_w3<<<dim3(256, 36, 2), 256, 0, stream>>>(cls_w, reg_w, wc, wr);
    cvt_w1<<<1, 256, 0, stream>>>(cls_fw, w1c);
    zero_halo<<<100, 256, 0, stream>>>(actC, actA0, actB0, actA1, actB1);
    cvt_in<<<dim3(256, 5, 4), 256, 0, stream>>>(
        (const float*)d_in[0], (const float*)d_in[1], (const float*)d_in[2],
        (const float*)d_in[3], (const float*)d_in[4], actC);

    unsigned short* srcs[4][2] = {{actC, actC}, {actA0, actA1}, {actB0, actB1}, {actA0, actA1}};
    unsigned short* dsts[4][2] = {{actA0, actA1}, {actB0, actB1}, {actA0, actA1}, {actB0, actB1}};
    for (int s = 0; s < 4; s++) {
        conv3x3_mfma<<<dim3(86, 1, 8), 512, 0, stream>>>(
            srcs[s][0], srcs[s][1], dsts[s][0], dsts[s][1],
            wc + (size_t)s * WSTEP, wr + (size_t)s * WSTEP,
            cls_s + s * 256, cls_b + s * 256, reg_s + s * 256, reg_b + s * 256);
    }

    final_cls<<<dim3(128, 5, 4), 256, 0, stream>>>(actB0, w1c, cls_fb, out);
    final_reg<<<dim3(64, 5, 4), 256, 0, stream>>>(actB1, reg_fw, reg_fb, out);
}

// Round 9
// 1073.414 us; speedup vs baseline: 2.7021x; 2.7021x over previous
//
#include <hip/hip_runtime.h>

typedef __attribute__((ext_vector_type(8))) short short8;
typedef __attribute__((ext_vector_type(4))) float f32x4;

#define ACT_P 23384064ul       /* padded: sum(HpWp)*256*4n */
#define WSTEP 589824           /* 9 tap * 32 ci8 * 256 co * 8 */

__device__ unsigned short g_actC[ACT_P];
__device__ unsigned short g_actA0[ACT_P];
__device__ unsigned short g_actB0[ACT_P];
__device__ unsigned short g_actA1[ACT_P];
__device__ unsigned short g_actB1[ACT_P];
__device__ unsigned short g_wc[4 * WSTEP];
__device__ unsigned short g_wr[4 * WSTEP];
__device__ unsigned short g_w1c[80 * 256];

__constant__ int      C_W[5]    = {128, 64, 32, 16, 8};
__constant__ int      C_WP[5]   = {130, 66, 34, 18, 10};
__constant__ int      C_HWP[5]  = {16900, 4356, 1156, 324, 100};
__constant__ int      C_LW[5]   = {7, 6, 5, 4, 3};
__constant__ int      C_LXT[5]  = {4, 3, 2, 1, 0};          // log2(W/8 x-tiles)
__constant__ int      C_PREF[5] = {0, 128, 160, 168, 170};  // tile prefix (171 total)
__constant__ int      C_HW[5]   = {16384, 4096, 1024, 256, 64};
__constant__ unsigned C_LOFFP[5]= {0u, 17305600u, 21766144u, 22949888u, 23281664u};
__constant__ unsigned C_CLSO[5] = {0u, 5242880u, 6553600u, 6881280u, 6963200u};
__constant__ unsigned C_REGO[5] = {6983680u, 7245824u, 7311360u, 7327744u, 7331840u};
__constant__ unsigned C_CENTO[5]= {7332864u, 7398400u, 7414784u, 7418880u, 7419904u};
__constant__ float    C_STRF[5] = {8.f, 16.f, 32.f, 64.f, 128.f};

static __device__ __forceinline__ unsigned short f2bf(float f) {
    unsigned u = __float_as_uint(f);
    unsigned r = (u + 0x7FFFu + ((u >> 16) & 1u)) >> 16;
    return (unsigned short)r;
}
static __device__ __forceinline__ float bf2f(unsigned short b) {
    return __uint_as_float(((unsigned)b) << 16);
}

// inline-asm global b128 loads with immediate offsets: cannot be deleted or
// re-scheduled by hipcc; one VALU-computed address serves 4 loads.
#define GLOAD0(dst, ptr) \
    asm volatile("global_load_dwordx4 %0, %1, off" : "=v"(dst) : "v"(ptr))
#define GLOAD_OFF(dst, ptr, imm) \
    asm volatile("global_load_dwordx4 %0, %1, off offset:" #imm : "=v"(dst) : "v"(ptr))

// counted vmcnt wait + scheduling fence; n is compile-time after unroll,
// the switch folds to a single literal s_waitcnt.
static __device__ __forceinline__ void vmwait(int n) {
    switch (n) {
    case 0:  asm volatile("s_waitcnt vmcnt(0)"  ::: "memory"); break;
    case 1:  asm volatile("s_waitcnt vmcnt(1)"  ::: "memory"); break;
    case 2:  asm volatile("s_waitcnt vmcnt(2)"  ::: "memory"); break;
    case 3:  asm volatile("s_waitcnt vmcnt(3)"  ::: "memory"); break;
    case 4:  asm volatile("s_waitcnt vmcnt(4)"  ::: "memory"); break;
    case 5:  asm volatile("s_waitcnt vmcnt(5)"  ::: "memory"); break;
    case 6:  asm volatile("s_waitcnt vmcnt(6)"  ::: "memory"); break;
    case 7:  asm volatile("s_waitcnt vmcnt(7)"  ::: "memory"); break;
    case 8:  asm volatile("s_waitcnt vmcnt(8)"  ::: "memory"); break;
    case 9:  asm volatile("s_waitcnt vmcnt(9)"  ::: "memory"); break;
    case 10: asm volatile("s_waitcnt vmcnt(10)" ::: "memory"); break;
    case 11: asm volatile("s_waitcnt vmcnt(11)" ::: "memory"); break;
    case 12: asm volatile("s_waitcnt vmcnt(12)" ::: "memory"); break;
    case 13: asm volatile("s_waitcnt vmcnt(13)" ::: "memory"); break;
    case 14: asm volatile("s_waitcnt vmcnt(14)" ::: "memory"); break;
    default: asm volatile("s_waitcnt vmcnt(15)" ::: "memory"); break;
    }
    __builtin_amdgcn_sched_barrier(0);
}

// ---------------------------------------------------------------------------
// weight convert: (4,256,256,3,3) fp32 -> [step][tap(9)][ci8(32)][co(256)][8] bf16
// ---------------------------------------------------------------------------
__global__ __launch_bounds__(256) void cvt_w3(
    const float* __restrict__ wc, const float* __restrict__ wr,
    unsigned short* __restrict__ oc, unsigned short* __restrict__ orr)
{
    const int co = blockIdx.x, sm = blockIdx.y, head = blockIdx.z;
    const int step = sm / 9, tap = sm - step * 9;
    const int ci = threadIdx.x;
    const float* w = head ? wr : wc;
    unsigned short* o = head ? orr : oc;
    o[(((size_t)sm * 32 + (ci >> 3)) * 256 + co) * 8 + (ci & 7)] =
        f2bf(w[(((size_t)step * 256 + co) * 256 + ci) * 9 + tap]);
}

__global__ __launch_bounds__(256) void cvt_w1(
    const float* __restrict__ w, unsigned short* __restrict__ o)
{
    for (int idx = threadIdx.x; idx < 80 * 256; idx += 256)
        o[idx] = f2bf(w[idx]);
}

// ---------------------------------------------------------------------------
// zero the 1-px halo border of every level/n of all 5 padded buffers
// ---------------------------------------------------------------------------
__global__ __launch_bounds__(256) void zero_halo(
    unsigned short* c, unsigned short* a0, unsigned short* b0,
    unsigned short* a1, unsigned short* b1)
{
    unsigned short* bufs[5] = {c, a0, b0, a1, b1};
    const int bid = blockIdx.x;
    const int buf = bid / 20, r = bid - buf * 20, lvl = r >> 2, n = r & 3;
    const int Wp = C_WP[lvl], Hp = Wp;
    unsigned short* base = bufs[buf] + C_LOFFP[lvl] + (size_t)n * C_HWP[lvl] * 256;
    const int hc = 2 * Wp + 2 * (Hp - 2);
    uint4 z; z.x = z.y = z.z = z.w = 0u;
    for (int idx = threadIdx.x; idx < hc * 32; idx += 256) {
        int pos = idx >> 5, q = idx & 31;
        int row, col;
        if (pos < 2 * Wp) { row = (pos >= Wp) ? (Hp - 1) : 0; col = (pos >= Wp) ? pos - Wp : pos; }
        else { int rem = pos - 2 * Wp; row = 1 + (rem >> 1); col = (rem & 1) ? (Wp - 1) : 0; }
        *(uint4*)(base + ((size_t)(row * Wp + col) << 8) + q * 8) = z;
    }
}

// ---------------------------------------------------------------------------
// input convert: fp32 NCHW -> bf16 padded NHWC.
// ---------------------------------------------------------------------------
__global__ __launch_bounds__(256) void cvt_in(
    const float* __restrict__ f0, const float* __restrict__ f1,
    const float* __restrict__ f2, const float* __restrict__ f3,
    const float* __restrict__ f4, unsigned short* __restrict__ dstC)
{
    const int lvl = blockIdx.y, n = blockIdx.z;
    const int HW = C_HW[lvl];
    const int p0 = blockIdx.x * 64;
    if (p0 >= HW) return;
    const int W = C_W[lvl], lw = C_LW[lvl], Wp = C_WP[lvl];
    const float* fp[5] = {f0, f1, f2, f3, f4};
    const float* src = fp[lvl] + (size_t)n * 256 * HW;
    unsigned short* dst = dstC + C_LOFFP[lvl] + (size_t)n * C_HWP[lvl] * 256;
    const int tid = threadIdx.x;
    __shared__ float ts[64][65];

    for (int cc = 0; cc < 256; cc += 64) {
        for (int idx = tid; idx < 64 * 64; idx += 256) {
            int ci = idx >> 6, p = idx & 63;
            ts[ci][p] = src[(size_t)(cc + ci) * HW + p0 + p];
        }
        __syncthreads();
        for (int idx = tid; idx < 64 * 64; idx += 256) {
            int p = idx >> 6, ci = idx & 63;
            int gp = p0 + p, y = gp >> lw, x = gp & (W - 1);
            dst[(size_t)((y + 1) * Wp + x + 1) * 256 + cc + ci] = f2bf(ts[ci][p]);
        }
        __syncthreads();
    }
}

// ---------------------------------------------------------------------------
// 3x3 conv + BN + ReLU, bf16 MFMA implicit GEMM.
// Block = 512 thr = 8 waves (4 coq x 2 xh): tile 256 co x 128 px (16y x 8x).
// Wave = 64 co x 64 px (16y x 4x), acc 4x4 f32x4 (64 AGPR).  1 block/CU.
// == r7 structure (best verified: 217us, 42% MfmaUtil, no spill) ==
// HARD CONSTRAINT (r8 lesson): 8-wave blocks cap at 256 regs/wave total
// (VGPR pool), so acc[4][4] is the max accumulator; (512,1) does NOT give
// 512 regs.
// r9 change: AITER-style fine-grained interleave.  Per tap, the single
// vmcnt(12) + 16-MFMA cluster is split into 4 groups: wait only for the
// mf-th weight load (vmcnt(4*lead + 3-mf)) then run its 4 MFMAs (~64cyc),
// overlapping the drain of the remaining loads with compute.  r7's
// monolithic wait serialized the 4-load drain against the MFMA cluster
// in lockstep across waves -> 840 idle cyc/tap/SIMD.
// grid: (171 packed tiles, 1, 8 = head*4+n).
// ---------------------------------------------------------------------------
__global__ __launch_bounds__(512, 2) void conv3x3_mfma(
    const unsigned short* __restrict__ src0, const unsigned short* __restrict__ src1,
    unsigned short* __restrict__ dst0, unsigned short* __restrict__ dst1,
    const unsigned short* __restrict__ wt0, const unsigned short* __restrict__ wt1,
    const float* __restrict__ sc0, const float* __restrict__ bi0,
    const float* __restrict__ sc1, const float* __restrict__ bi1)
{
    int tc = blockIdx.x;
    const int lvl = (tc >= 128) + (tc >= 160) + (tc >= 168) + (tc >= 170);
    tc -= C_PREF[lvl];
    const int head = blockIdx.z >> 2, n = blockIdx.z & 3;

    const int W = C_W[lvl], H = W, Wp = C_WP[lvl];
    const int lxt = C_LXT[lvl];
    const int tx = tc & ((1 << lxt) - 1), ty = tc >> lxt;
    const int x0 = tx * 8, y0 = ty * 16;

    const unsigned short* src = head ? src1 : src0;
    unsigned short*       dst = head ? dst1 : dst0;
    const unsigned short* wt  = head ? wt1 : wt0;
    const float* sc = head ? sc1 : sc0;
    const float* bi = head ? bi1 : bi0;
    const size_t actOff = (size_t)C_LOFFP[lvl] + (size_t)n * C_HWP[lvl] * 256;
    src += actOff; dst += actOff;

    const int tid = threadIdx.x;
    const int lane = tid & 63, wid = tid >> 6;
    const int l16 = lane & 15, quad = lane >> 4;
    const int coq = wid & 3, xh = wid >> 2;
    const int cow = coq * 64, jw = xh * 4;

    // LDS: [g(32)][x(10)][y(19)] x 16B = 97280 B (full 256 ci)
    __shared__ unsigned short B_s[32 * 10 * 19 * 8];
    char* Bb = (char*)B_s;

    // ---- staging addresses: half = 16 g-slices; 2880 slots ----
    int goff[6], ldso[6];
#pragma unroll
    for (int it = 0; it < 6; it++) {
        int slot = tid + it * 512;
        if (slot > 2879) slot = 2879;
        int g = slot & 15, p = slot >> 4;       // p = y*10 + x, p < 180
        int y = (p * 205) >> 11;                // /10
        int x = p - y * 10;
        int gyp = y0 + y; if (gyp > Wp - 1) gyp = Wp - 1;   // lvl4 clamps to zero halo row
        goff[it] = (((gyp * Wp) + x0 + x) << 8) + g * 8;
        ldso[it] = ((g * 10 + x) * 19 + y) * 16;
    }

    f32x4 acc[4][4];
#pragma unroll
    for (int mf = 0; mf < 4; mf++)
#pragma unroll
        for (int nf = 0; nf < 4; nf++) acc[mf][nf] = (f32x4){0.f, 0.f, 0.f, 0.f};

    // ---- stage half-0 (transient) ----
    {
        uint4 tv[6];
#pragma unroll
        for (int it = 0; it < 6; it++) tv[it] = *(const uint4*)(src + goff[it]);
#pragma unroll
        for (int it = 0; it < 6; it++) *(uint4*)(Bb + ldso[it]) = tv[it];
    }
    __syncthreads();

#pragma unroll
    for (int ph = 0; ph < 2; ph++) {
        if (ph == 1) {
            // transient half-1 staging; writes g16..31 (disjoint from ph0 reads)
            uint4 tv[6];
#pragma unroll
            for (int it = 0; it < 6; it++) tv[it] = *(const uint4*)(src + goff[it] + 128);
#pragma unroll
            for (int it = 0; it < 6; it++) *(uint4*)(Bb + ldso[it] + 48640) = tv[it];
            __syncthreads();
        }

        short8 Af[4][4];    // depth-3 in-flight + 1 in-use (asm-pinned)
        short8 Bf[2][6];    // double-buffered LDS fragments per (c4,kh)

        auto wBase = [&](int T) -> const unsigned short* {
            const int c4 = T / 9, tap = T - 9 * c4;
            const int c32 = ph * 4 + c4;
            return wt + (((tap * 32 + c32 * 4 + quad) * 256) + cow + l16) * 8;
        };
        auto issueA = [&](int T, short8* dA) {
            const unsigned short* p = wBase(T);
            GLOAD0(dA[0], p);
            GLOAD_OFF(dA[1], p, 256);
            GLOAD_OFF(dA[2], p, 512);
            GLOAD_OFF(dA[3], p, 768);
        };
        auto loadB = [&](int g, short8* dB) {    // g = c4*3 + kh, 0..11
            const int c4 = g / 3, kh = g - 3 * c4;
            const int c32 = ph * 4 + c4;
#pragma unroll
            for (int j = 0; j < 6; j++)
                dB[j] = *(const short8*)(Bb +
                    (((c32 * 4 + quad) * 10 + jw + j) * 19 + l16 + kh) * 16);
        };

        // prologue: issue taps 0..2 (12 loads in flight)
#pragma unroll
        for (int t = 0; t < 3; t++) issueA(t, Af[t]);
        loadB(0, Bf[0]);

#pragma unroll
        for (int T = 0; T < 36; T++) {
            const int g = T / 3, kw = T - g * 3;
            if (T + 3 < 36) issueA(T + 3, Af[(T + 3) & 3]);
            if (kw == 0 && g + 1 < 12) loadB(g + 1, Bf[(g + 1) & 1]);
            // taps still in flight beyond T (compile-time after unroll)
            const int lead = (T + 3 < 36) ? 3 : (35 - T);
            const short8* Ac = Af[T & 3];
            const short8* Bc = Bf[g & 1];
#pragma unroll
            for (int mf = 0; mf < 4; mf++) {
                // wait ONLY for tap T's mf-th load; rest keep draining
                vmwait(4 * lead + (3 - mf));
#pragma unroll
                for (int nf = 0; nf < 4; nf++)
                    acc[mf][nf] = __builtin_amdgcn_mfma_f32_16x16x32_bf16(
                        Ac[mf], Bc[nf + kw], acc[mf][nf], 0, 0, 0);
            }
        }
    }

    // ---- epilogue: BN + ReLU + cvt bf16, padded NHWC store ----
    const int gy = y0 + l16;
    if (gy < H) {
#pragma unroll
        for (int mf = 0; mf < 4; mf++) {
            const int co4 = cow + mf * 16 + quad * 4;
            const f32x4 s4 = *(const f32x4*)(sc + co4);
            const f32x4 b4 = *(const f32x4*)(bi + co4);
#pragma unroll
            for (int nf = 0; nf < 4; nf++) {
                const int gx = x0 + jw + nf;
                f32x4 v = acc[mf][nf];
                ushort4 o;
                o.x = f2bf(fmaxf(v[0] * s4[0] + b4[0], 0.f));
                o.y = f2bf(fmaxf(v[1] * s4[1] + b4[1], 0.f));
                o.z = f2bf(fmaxf(v[2] * s4[2] + b4[2], 0.f));
                o.w = f2bf(fmaxf(v[3] * s4[3] + b4[3], 0.f));
                *(ushort4*)(dst + ((size_t)((gy + 1) * Wp + gx + 1) * 256 + co4)) = o;
            }
        }
    }
}

// ---------------------------------------------------------------------------
// final 1x1 cls: 256 -> 80 + bias, MFMA, fp32 NCHW out (padded NHWC input).
// ---------------------------------------------------------------------------
__global__ __launch_bounds__(256) void final_cls(
    const unsigned short* __restrict__ act, const unsigned short* __restrict__ w,
    const float* __restrict__ bias, float* __restrict__ out)
{
    const int lvl = blockIdx.y, n = blockIdx.z;
    const int HW = C_HW[lvl];
    const int p0 = blockIdx.x * 128;
    if (p0 >= HW) return;
    const int W = C_W[lvl], lw = C_LW[lvl], Wp = C_WP[lvl];

    const int tid = threadIdx.x;
    const int lane = tid & 63, wid = tid >> 6;
    const int l16 = lane & 15, quad = lane >> 4;

    const unsigned short* a = act + C_LOFFP[lvl] + (size_t)n * C_HWP[lvl] * 256;

    int px[2]; size_t aoff[2];
#pragma unroll
    for (int j = 0; j < 2; j++) {
        px[j] = p0 + wid * 32 + j * 16 + l16;
        int lpx = px[j] < HW ? px[j] : 0;
        int y = lpx >> lw, x = lpx & (W - 1);
        aoff[j] = (size_t)((y + 1) * Wp + x + 1) * 256;
    }

    f32x4 acc[5][2];
#pragma unroll
    for (int mf = 0; mf < 5; mf++) { acc[mf][0] = (f32x4){0,0,0,0}; acc[mf][1] = (f32x4){0,0,0,0}; }

    for (int cc = 0; cc < 256; cc += 32) {
        short8 b0 = *(const short8*)(a + aoff[0] + cc + quad * 8);
        short8 b1 = *(const short8*)(a + aoff[1] + cc + quad * 8);
#pragma unroll
        for (int mf = 0; mf < 5; mf++) {
            short8 av = *(const short8*)(w + (mf * 16 + l16) * 256 + cc + quad * 8);
            acc[mf][0] = __builtin_amdgcn_mfma_f32_16x16x32_bf16(av, b0, acc[mf][0], 0, 0, 0);
            acc[mf][1] = __builtin_amdgcn_mfma_f32_16x16x32_bf16(av, b1, acc[mf][1], 0, 0, 0);
        }
    }

    float* ob = out + C_CLSO[lvl] + (size_t)n * 80 * HW;
#pragma unroll
    for (int mf = 0; mf < 5; mf++) {
        const int co0 = mf * 16 + quad * 4;
#pragma unroll
        for (int j = 0; j < 2; j++) {
            if (px[j] < HW) {
#pragma unroll
                for (int r = 0; r < 4; r++)
                    ob[(size_t)(co0 + r) * HW + px[j]] = acc[mf][j][r] + bias[co0 + r];
            }
        }
    }
}

// ---------------------------------------------------------------------------
// final 1x1 reg: 256 -> 5 + bias; ch0 centerness, ch1..4 max(raw*stride,0).
// ---------------------------------------------------------------------------
__global__ __launch_bounds__(256) void final_reg(
    const unsigned short* __restrict__ act, const float* __restrict__ w,
    const float* __restrict__ bias, float* __restrict__ out)
{
    const int lvl = blockIdx.y, n = blockIdx.z;
    const int HW = C_HW[lvl];
    const int W = C_W[lvl], lw = C_LW[lvl], Wp = C_WP[lvl];
    const int tid = threadIdx.x;

    __shared__ float ws[5 * 256];
    for (int idx = tid; idx < 5 * 256; idx += 256) ws[idx] = w[idx];
    __syncthreads();

    const int px = blockIdx.x * 256 + tid;
    if (px >= HW) return;

    const int y = px >> lw, x = px & (W - 1);
    const unsigned short* a = act + C_LOFFP[lvl] + (size_t)n * C_HWP[lvl] * 256
                            + (size_t)((y + 1) * Wp + x + 1) * 256;
    float acc[5] = {0.f, 0.f, 0.f, 0.f, 0.f};

    for (int ci = 0; ci < 256; ci += 8) {
        ushort4 u0 = *(const ushort4*)(a + ci);
        ushort4 u1 = *(const ushort4*)(a + ci + 4);
        float xv[8] = {bf2f(u0.x), bf2f(u0.y), bf2f(u0.z), bf2f(u0.w),
                       bf2f(u1.x), bf2f(u1.y), bf2f(u1.z), bf2f(u1.w)};
#pragma unroll
        for (int j = 0; j < 5; j++) {
            const float* wj = &ws[j * 256 + ci];
#pragma unroll
            for (int k = 0; k < 8; k++) acc[j] = fmaf(xv[k], wj[k], acc[j]);
        }
    }

    const float strf = C_STRF[lvl];
    out[C_CENTO[lvl] + (size_t)n * HW + px] = acc[0] + bias[0];
    float* rb = out + C_REGO[lvl] + (size_t)n * 4 * HW;
#pragma unroll
    for (int j = 0; j < 4; j++)
        rb[(size_t)j * HW + px] = fmaxf((acc[j + 1] + bias[j + 1]) * strf, 0.f);
}

// ---------------------------------------------------------------------------
extern "C" void kernel_launch(void* const* d_in, const int* in_sizes, int n_in,
                              void* d_out, int out_size, void* d_ws, size_t ws_size,
                              hipStream_t stream)
{
    const float* cls_w  = (const float*)d_in[5];
    const float* cls_s  = (const float*)d_in[6];
    const float* cls_b  = (const float*)d_in[7];
    const float* cls_fw = (const float*)d_in[8];
    const float* cls_fb = (const float*)d_in[9];
    const float* reg_w  = (const float*)d_in[10];
    const float* reg_s  = (const float*)d_in[11];
    const float* reg_b  = (const float*)d_in[12];
    const float* reg_fw = (const float*)d_in[13];
    const float* reg_fb = (const float*)d_in[14];
    float* out = (float*)d_out;

    unsigned short *actC, *actA0, *actB0, *actA1, *actB1, *wc, *wr, *w1c;
    hipGetSymbolAddress((void**)&actC,  HIP_SYMBOL(g_actC));
    hipGetSymbolAddress((void**)&actA0, HIP_SYMBOL(g_actA0));
    hipGetSymbolAddress((void**)&actB0, HIP_SYMBOL(g_actB0));
    hipGetSymbolAddress((void**)&actA1, HIP_SYMBOL(g_actA1));
    hipGetSymbolAddress((void**)&actB1, HIP_SYMBOL(g_actB1));
    hipGetSymbolAddress((void**)&wc,    HIP_SYMBOL(g_wc));
    hipGetSymbolAddress((void**)&wr,    HIP_SYMBOL(g_wr));
    hipGetSymbolAddress((void**)&w1c,   HIP_SYMBOL(g_w1c));

    cvt_w3<<<dim3(256, 36, 2), 256, 0, stream>>>(cls_w, reg_w, wc, wr);
    cvt_w1<<<1, 256, 0, stream>>>(cls_fw, w1c);
    zero_halo<<<100, 256, 0, stream>>>(actC, actA0, actB0, actA1, actB1);
    cvt_in<<<dim3(256, 5, 4), 256, 0, stream>>>(
        (const float*)d_in[0], (const float*)d_in[1], (const float*)d_in[2],
        (const float*)d_in[3], (const float*)d_in[4], actC);

    unsigned short* srcs[4][2] = {{actC, actC}, {actA0, actA1}, {actB0, actB1}, {actA0, actA1}};
    unsigned short* dsts[4][2] = {{actA0, actA1}, {actB0, actB1}, {actA0, actA1}, {actB0, actB1}};
    for (int s = 0; s < 4; s++) {
        conv3x3_mfma<<<dim3(171, 1, 8), 512, 0, stream>>>(
            srcs[s][0], srcs[s][1], dsts[s][0], dsts[s][1],
            wc + (size_t)s * WSTEP, wr + (size_t)s * WSTEP,
            cls_s + s * 256, cls_b + s * 256, reg_s + s * 256, reg_b + s * 256);
    }

    final_cls<<<dim3(128, 5, 4), 256, 0, stream>>>(actB0, w1c, cls_fb, out);
    final_reg<<<dim3(64, 5, 4), 256, 0, stream>>>(actB1, reg_fw, reg_fb, out);
}

// Round 10
// 945.736 us; speedup vs baseline: 3.0669x; 1.1350x over previous
//
#include <hip/hip_runtime.h>

typedef __attribute__((ext_vector_type(8))) short short8;
typedef __attribute__((ext_vector_type(4))) float f32x4;

#define ACT_P 23384064ul       /* padded: sum(HpWp)*256*4n */
#define WSTEP 589824           /* 9 tap * 32 ci8 * 256 co * 8 */

__device__ unsigned short g_actC[ACT_P];
__device__ unsigned short g_actA0[ACT_P];
__device__ unsigned short g_actB0[ACT_P];
__device__ unsigned short g_actA1[ACT_P];
__device__ unsigned short g_actB1[ACT_P];
__device__ unsigned short g_wc[4 * WSTEP];
__device__ unsigned short g_wr[4 * WSTEP];
__device__ unsigned short g_w1c[80 * 256];

__constant__ int      C_W[5]    = {128, 64, 32, 16, 8};
__constant__ int      C_WP[5]   = {130, 66, 34, 18, 10};
__constant__ int      C_HWP[5]  = {16900, 4356, 1156, 324, 100};
__constant__ int      C_LW[5]   = {7, 6, 5, 4, 3};
__constant__ int      C_LXT[5]  = {4, 3, 2, 1, 0};          // log2(W/8 x-tiles)
__constant__ int      C_PREF[5] = {0, 128, 160, 168, 170};  // tile prefix (171 total)
__constant__ int      C_HW[5]   = {16384, 4096, 1024, 256, 64};
__constant__ unsigned C_LOFFP[5]= {0u, 17305600u, 21766144u, 22949888u, 23281664u};
__constant__ unsigned C_CLSO[5] = {0u, 5242880u, 6553600u, 6881280u, 6963200u};
__constant__ unsigned C_REGO[5] = {6983680u, 7245824u, 7311360u, 7327744u, 7331840u};
__constant__ unsigned C_CENTO[5]= {7332864u, 7398400u, 7414784u, 7418880u, 7419904u};
__constant__ float    C_STRF[5] = {8.f, 16.f, 32.f, 64.f, 128.f};

static __device__ __forceinline__ unsigned short f2bf(float f) {
    unsigned u = __float_as_uint(f);
    unsigned r = (u + 0x7FFFu + ((u >> 16) & 1u)) >> 16;
    return (unsigned short)r;
}
static __device__ __forceinline__ float bf2f(unsigned short b) {
    return __uint_as_float(((unsigned)b) << 16);
}

// inline-asm global b128 loads with immediate offsets: cannot be deleted or
// re-scheduled by hipcc; one VALU-computed address serves both loads.
#define GLOAD0(dst, ptr) \
    asm volatile("global_load_dwordx4 %0, %1, off" : "=v"(dst) : "v"(ptr))
#define GLOAD_OFF(dst, ptr, imm) \
    asm volatile("global_load_dwordx4 %0, %1, off offset:" #imm : "=v"(dst) : "v"(ptr))

// counted vmcnt wait + scheduling fence; n is compile-time after unroll.
static __device__ __forceinline__ void vmwait(int n) {
    switch (n) {
    case 0:  asm volatile("s_waitcnt vmcnt(0)"  ::: "memory"); break;
    case 1:  asm volatile("s_waitcnt vmcnt(1)"  ::: "memory"); break;
    case 2:  asm volatile("s_waitcnt vmcnt(2)"  ::: "memory"); break;
    case 3:  asm volatile("s_waitcnt vmcnt(3)"  ::: "memory"); break;
    case 4:  asm volatile("s_waitcnt vmcnt(4)"  ::: "memory"); break;
    case 5:  asm volatile("s_waitcnt vmcnt(5)"  ::: "memory"); break;
    case 6:  asm volatile("s_waitcnt vmcnt(6)"  ::: "memory"); break;
    case 7:  asm volatile("s_waitcnt vmcnt(7)"  ::: "memory"); break;
    case 8:  asm volatile("s_waitcnt vmcnt(8)"  ::: "memory"); break;
    default: asm volatile("s_waitcnt vmcnt(9)"  ::: "memory"); break;
    }
    __builtin_amdgcn_sched_barrier(0);
}

// ---------------------------------------------------------------------------
// weight convert: (4,256,256,3,3) fp32 -> [step][tap(9)][ci8(32)][co(256)][8] bf16
// ---------------------------------------------------------------------------
__global__ __launch_bounds__(256) void cvt_w3(
    const float* __restrict__ wc, const float* __restrict__ wr,
    unsigned short* __restrict__ oc, unsigned short* __restrict__ orr)
{
    const int co = blockIdx.x, sm = blockIdx.y, head = blockIdx.z;
    const int step = sm / 9, tap = sm - step * 9;
    const int ci = threadIdx.x;
    const float* w = head ? wr : wc;
    unsigned short* o = head ? orr : oc;
    o[(((size_t)sm * 32 + (ci >> 3)) * 256 + co) * 8 + (ci & 7)] =
        f2bf(w[(((size_t)step * 256 + co) * 256 + ci) * 9 + tap]);
}

__global__ __launch_bounds__(256) void cvt_w1(
    const float* __restrict__ w, unsigned short* __restrict__ o)
{
    for (int idx = threadIdx.x; idx < 80 * 256; idx += 256)
        o[idx] = f2bf(w[idx]);
}

// ---------------------------------------------------------------------------
// zero the 1-px halo border of every level/n of all 5 padded buffers
// ---------------------------------------------------------------------------
__global__ __launch_bounds__(256) void zero_halo(
    unsigned short* c, unsigned short* a0, unsigned short* b0,
    unsigned short* a1, unsigned short* b1)
{
    unsigned short* bufs[5] = {c, a0, b0, a1, b1};
    const int bid = blockIdx.x;
    const int buf = bid / 20, r = bid - buf * 20, lvl = r >> 2, n = r & 3;
    const int Wp = C_WP[lvl], Hp = Wp;
    unsigned short* base = bufs[buf] + C_LOFFP[lvl] + (size_t)n * C_HWP[lvl] * 256;
    const int hc = 2 * Wp + 2 * (Hp - 2);
    uint4 z; z.x = z.y = z.z = z.w = 0u;
    for (int idx = threadIdx.x; idx < hc * 32; idx += 256) {
        int pos = idx >> 5, q = idx & 31;
        int row, col;
        if (pos < 2 * Wp) { row = (pos >= Wp) ? (Hp - 1) : 0; col = (pos >= Wp) ? pos - Wp : pos; }
        else { int rem = pos - 2 * Wp; row = 1 + (rem >> 1); col = (rem & 1) ? (Wp - 1) : 0; }
        *(uint4*)(base + ((size_t)(row * Wp + col) << 8) + q * 8) = z;
    }
}

// ---------------------------------------------------------------------------
// input convert: fp32 NCHW -> bf16 padded NHWC.
// ---------------------------------------------------------------------------
__global__ __launch_bounds__(256) void cvt_in(
    const float* __restrict__ f0, const float* __restrict__ f1,
    const float* __restrict__ f2, const float* __restrict__ f3,
    const float* __restrict__ f4, unsigned short* __restrict__ dstC)
{
    const int lvl = blockIdx.y, n = blockIdx.z;
    const int HW = C_HW[lvl];
    const int p0 = blockIdx.x * 64;
    if (p0 >= HW) return;
    const int W = C_W[lvl], lw = C_LW[lvl], Wp = C_WP[lvl];
    const float* fp[5] = {f0, f1, f2, f3, f4};
    const float* src = fp[lvl] + (size_t)n * 256 * HW;
    unsigned short* dst = dstC + C_LOFFP[lvl] + (size_t)n * C_HWP[lvl] * 256;
    const int tid = threadIdx.x;
    __shared__ float ts[64][65];

    for (int cc = 0; cc < 256; cc += 64) {
        for (int idx = tid; idx < 64 * 64; idx += 256) {
            int ci = idx >> 6, p = idx & 63;
            ts[ci][p] = src[(size_t)(cc + ci) * HW + p0 + p];
        }
        __syncthreads();
        for (int idx = tid; idx < 64 * 64; idx += 256) {
            int p = idx >> 6, ci = idx & 63;
            int gp = p0 + p, y = gp >> lw, x = gp & (W - 1);
            dst[(size_t)((y + 1) * Wp + x + 1) * 256 + cc + ci] = f2bf(ts[ci][p]);
        }
        __syncthreads();
    }
}

// ---------------------------------------------------------------------------
// 3x3 conv + BN + ReLU, bf16 MFMA implicit GEMM.
// Block = 512 thr = 8 waves, CO-SPLIT: each wave owns a distinct 32-co slice
// (cow = wid*32) over the FULL 128-px tile (16y x 8x).  acc 2x8 f32x4
// (64 AGPR).  1 block/CU (97KB LDS).
// r9 diagnosis: weight L2 drain (2.3MB/block: 2 xh waves fetched IDENTICAL
// co-ranges) ~= MFMA floor (45k cyc) -> 1:1 contention capped MfmaUtil ~45%.
// Co-split removes the duplication: 2 weight b128/wave/tap, 16KB/CU/tap ->
// drain 21k cyc/block, off the critical path.  B-fragments shared via LDS
// (each wave reads the full 10-wide Bf row; ~4k cyc hidden under MFMA).
// Keep r9's asm depth-3 pipeline: per tap issue tap T+3's 2 loads, then per
// mf wait vmcnt(2*lead + 1-mf) and run 8 MFMAs (fine-grained drain overlap).
// HARD CONSTRAINT (r8): 8-wave blocks cap at 256 regs/wave; live set here
// ~= 64 AGPR + Bf 80 + Af 32 + addr ~ 150 arch VGPR -> no spill.
// grid: (171 packed tiles, 1, 8 = head*4+n).
// ---------------------------------------------------------------------------
__global__ __launch_bounds__(512, 2) void conv3x3_mfma(
    const unsigned short* __restrict__ src0, const unsigned short* __restrict__ src1,
    unsigned short* __restrict__ dst0, unsigned short* __restrict__ dst1,
    const unsigned short* __restrict__ wt0, const unsigned short* __restrict__ wt1,
    const float* __restrict__ sc0, const float* __restrict__ bi0,
    const float* __restrict__ sc1, const float* __restrict__ bi1)
{
    int tc = blockIdx.x;
    const int lvl = (tc >= 128) + (tc >= 160) + (tc >= 168) + (tc >= 170);
    tc -= C_PREF[lvl];
    const int head = blockIdx.z >> 2, n = blockIdx.z & 3;

    const int W = C_W[lvl], H = W, Wp = C_WP[lvl];
    const int lxt = C_LXT[lvl];
    const int tx = tc & ((1 << lxt) - 1), ty = tc >> lxt;
    const int x0 = tx * 8, y0 = ty * 16;

    const unsigned short* src = head ? src1 : src0;
    unsigned short*       dst = head ? dst1 : dst0;
    const unsigned short* wt  = head ? wt1 : wt0;
    const float* sc = head ? sc1 : sc0;
    const float* bi = head ? bi1 : bi0;
    const size_t actOff = (size_t)C_LOFFP[lvl] + (size_t)n * C_HWP[lvl] * 256;
    src += actOff; dst += actOff;

    const int tid = threadIdx.x;
    const int lane = tid & 63, wid = tid >> 6;
    const int l16 = lane & 15, quad = lane >> 4;
    const int cow = wid * 32;              // co-split: 8 waves x 32 co

    // LDS: [g(32)][x(10)][y(19)] x 16B = 97280 B (full 256 ci)
    __shared__ unsigned short B_s[32 * 10 * 19 * 8];
    char* Bb = (char*)B_s;

    // ---- staging addresses: half = 16 g-slices; 2880 slots ----
    int goff[6], ldso[6];
#pragma unroll
    for (int it = 0; it < 6; it++) {
        int slot = tid + it * 512;
        if (slot > 2879) slot = 2879;
        int g = slot & 15, p = slot >> 4;       // p = y*10 + x, p < 180
        int y = (p * 205) >> 11;                // /10
        int x = p - y * 10;
        int gyp = y0 + y; if (gyp > Wp - 1) gyp = Wp - 1;   // lvl4 clamps to zero halo row
        goff[it] = (((gyp * Wp) + x0 + x) << 8) + g * 8;
        ldso[it] = ((g * 10 + x) * 19 + y) * 16;
    }

    f32x4 acc[2][8];
#pragma unroll
    for (int mf = 0; mf < 2; mf++)
#pragma unroll
        for (int nf = 0; nf < 8; nf++) acc[mf][nf] = (f32x4){0.f, 0.f, 0.f, 0.f};

    // ---- stage half-0 (transient) ----
    {
        uint4 tv[6];
#pragma unroll
        for (int it = 0; it < 6; it++) tv[it] = *(const uint4*)(src + goff[it]);
#pragma unroll
        for (int it = 0; it < 6; it++) *(uint4*)(Bb + ldso[it]) = tv[it];
    }
    __syncthreads();

#pragma unroll
    for (int ph = 0; ph < 2; ph++) {
        if (ph == 1) {
            // transient half-1 staging; writes g16..31 (disjoint from ph0 reads)
            uint4 tv[6];
#pragma unroll
            for (int it = 0; it < 6; it++) tv[it] = *(const uint4*)(src + goff[it] + 128);
#pragma unroll
            for (int it = 0; it < 6; it++) *(uint4*)(Bb + ldso[it] + 48640) = tv[it];
            __syncthreads();
        }

        short8 Af[4][2];    // depth-3 in-flight + 1 in-use (asm-pinned)
        short8 Bf[2][10];   // double-buffered LDS fragments per (c4,kh)

        auto wBase = [&](int T) -> const unsigned short* {
            const int c4 = T / 9, tap = T - 9 * c4;
            const int c32 = ph * 4 + c4;
            return wt + (((tap * 32 + c32 * 4 + quad) * 256) + cow + l16) * 8;
        };
        auto issueA = [&](int T, short8* dA) {
            const unsigned short* p = wBase(T);
            GLOAD0(dA[0], p);
            GLOAD_OFF(dA[1], p, 256);
        };
        auto loadB = [&](int g, short8* dB) {    // g = c4*3 + kh, 0..11
            const int c4 = g / 3, kh = g - 3 * c4;
            const int c32 = ph * 4 + c4;
#pragma unroll
            for (int j = 0; j < 10; j++)
                dB[j] = *(const short8*)(Bb +
                    (((c32 * 4 + quad) * 10 + j) * 19 + l16 + kh) * 16);
        };

        // prologue: issue taps 0..2 (6 loads in flight)
#pragma unroll
        for (int t = 0; t < 3; t++) issueA(t, Af[t]);
        loadB(0, Bf[0]);

#pragma unroll
        for (int T = 0; T < 36; T++) {
            const int g = T / 3, kw = T - g * 3;
            if (T + 3 < 36) issueA(T + 3, Af[(T + 3) & 3]);
            if (kw == 0 && g + 1 < 12) loadB(g + 1, Bf[(g + 1) & 1]);
            // taps still in flight beyond T (compile-time after unroll)
            const int lead = (T + 3 < 36) ? 3 : (35 - T);
            const short8* Ac = Af[T & 3];
            const short8* Bc = Bf[g & 1];
#pragma unroll
            for (int mf = 0; mf < 2; mf++) {
                // wait ONLY for tap T's mf-th load; rest keep draining
                vmwait(2 * lead + (1 - mf));
#pragma unroll
                for (int nf = 0; nf < 8; nf++)
                    acc[mf][nf] = __builtin_amdgcn_mfma_f32_16x16x32_bf16(
                        Ac[mf], Bc[nf + kw], acc[mf][nf], 0, 0, 0);
            }
        }
    }

    // ---- epilogue: BN + ReLU + cvt bf16, padded NHWC store ----
    const int gy = y0 + l16;
    if (gy < H) {
#pragma unroll
        for (int mf = 0; mf < 2; mf++) {
            const int co4 = cow + mf * 16 + quad * 4;
            const f32x4 s4 = *(const f32x4*)(sc + co4);
            const f32x4 b4 = *(const f32x4*)(bi + co4);
#pragma unroll
            for (int nf = 0; nf < 8; nf++) {
                const int gx = x0 + nf;
                f32x4 v = acc[mf][nf];
                ushort4 o;
                o.x = f2bf(fmaxf(v[0] * s4[0] + b4[0], 0.f));
                o.y = f2bf(fmaxf(v[1] * s4[1] + b4[1], 0.f));
                o.z = f2bf(fmaxf(v[2] * s4[2] + b4[2], 0.f));
                o.w = f2bf(fmaxf(v[3] * s4[3] + b4[3], 0.f));
                *(ushort4*)(dst + ((size_t)((gy + 1) * Wp + gx + 1) * 256 + co4)) = o;
            }
        }
    }
}

// ---------------------------------------------------------------------------
// final 1x1 cls: 256 -> 80 + bias, MFMA, fp32 NCHW out (padded NHWC input).
// ---------------------------------------------------------------------------
__global__ __launch_bounds__(256) void final_cls(
    const unsigned short* __restrict__ act, const unsigned short* __restrict__ w,
    const float* __restrict__ bias, float* __restrict__ out)
{
    const int lvl = blockIdx.y, n = blockIdx.z;
    const int HW = C_HW[lvl];
    const int p0 = blockIdx.x * 128;
    if (p0 >= HW) return;
    const int W = C_W[lvl], lw = C_LW[lvl], Wp = C_WP[lvl];

    const int tid = threadIdx.x;
    const int lane = tid & 63, wid = tid >> 6;
    const int l16 = lane & 15, quad = lane >> 4;

    const unsigned short* a = act + C_LOFFP[lvl] + (size_t)n * C_HWP[lvl] * 256;

    int px[2]; size_t aoff[2];
#pragma unroll
    for (int j = 0; j < 2; j++) {
        px[j] = p0 + wid * 32 + j * 16 + l16;
        int lpx = px[j] < HW ? px[j] : 0;
        int y = lpx >> lw, x = lpx & (W - 1);
        aoff[j] = (size_t)((y + 1) * Wp + x + 1) * 256;
    }

    f32x4 acc[5][2];
#pragma unroll
    for (int mf = 0; mf < 5; mf++) { acc[mf][0] = (f32x4){0,0,0,0}; acc[mf][1] = (f32x4){0,0,0,0}; }

    for (int cc = 0; cc < 256; cc += 32) {
        short8 b0 = *(const short8*)(a + aoff[0] + cc + quad * 8);
        short8 b1 = *(const short8*)(a + aoff[1] + cc + quad * 8);
#pragma unroll
        for (int mf = 0; mf < 5; mf++) {
            short8 av = *(const short8*)(w + (mf * 16 + l16) * 256 + cc + quad * 8);
            acc[mf][0] = __builtin_amdgcn_mfma_f32_16x16x32_bf16(av, b0, acc[mf][0], 0, 0, 0);
            acc[mf][1] = __builtin_amdgcn_mfma_f32_16x16x32_bf16(av, b1, acc[mf][1], 0, 0, 0);
        }
    }

    float* ob = out + C_CLSO[lvl] + (size_t)n * 80 * HW;
#pragma unroll
    for (int mf = 0; mf < 5; mf++) {
        const int co0 = mf * 16 + quad * 4;
#pragma unroll
        for (int j = 0; j < 2; j++) {
            if (px[j] < HW) {
#pragma unroll
                for (int r = 0; r < 4; r++)
                    ob[(size_t)(co0 + r) * HW + px[j]] = acc[mf][j][r] + bias[co0 + r];
            }
        }
    }
}

// ---------------------------------------------------------------------------
// final 1x1 reg: 256 -> 5 + bias; ch0 centerness, ch1..4 max(raw*stride,0).
// ---------------------------------------------------------------------------
__global__ __launch_bounds__(256) void final_reg(
    const unsigned short* __restrict__ act, const float* __restrict__ w,
    const float* __restrict__ bias, float* __restrict__ out)
{
    const int lvl = blockIdx.y, n = blockIdx.z;
    const int HW = C_HW[lvl];
    const int W = C_W[lvl], lw = C_LW[lvl], Wp = C_WP[lvl];
    const int tid = threadIdx.x;

    __shared__ float ws[5 * 256];
    for (int idx = tid; idx < 5 * 256; idx += 256) ws[idx] = w[idx];
    __syncthreads();

    const int px = blockIdx.x * 256 + tid;
    if (px >= HW) return;

    const int y = px >> lw, x = px & (W - 1);
    const unsigned short* a = act + C_LOFFP[lvl] + (size_t)n * C_HWP[lvl] * 256
                            + (size_t)((y + 1) * Wp + x + 1) * 256;
    float acc[5] = {0.f, 0.f, 0.f, 0.f, 0.f};

    for (int ci = 0; ci < 256; ci += 8) {
        ushort4 u0 = *(const ushort4*)(a + ci);
        ushort4 u1 = *(const ushort4*)(a + ci + 4);
        float xv[8] = {bf2f(u0.x), bf2f(u0.y), bf2f(u0.z), bf2f(u0.w),
                       bf2f(u1.x), bf2f(u1.y), bf2f(u1.z), bf2f(u1.w)};
#pragma unroll
        for (int j = 0; j < 5; j++) {
            const float* wj = &ws[j * 256 + ci];
#pragma unroll
            for (int k = 0; k < 8; k++) acc[j] = fmaf(xv[k], wj[k], acc[j]);
        }
    }

    const float strf = C_STRF[lvl];
    out[C_CENTO[lvl] + (size_t)n * HW + px] = acc[0] + bias[0];
    float* rb = out + C_REGO[lvl] + (size_t)n * 4 * HW;
#pragma unroll
    for (int j = 0; j < 4; j++)
        rb[(size_t)j * HW + px] = fmaxf((acc[j + 1] + bias[j + 1]) * strf, 0.f);
}

// ---------------------------------------------------------------------------
extern "C" void kernel_launch(void* const* d_in, const int* in_sizes, int n_in,
                              void* d_out, int out_size, void* d_ws, size_t ws_size,
                              hipStream_t stream)
{
    const float* cls_w  = (const float*)d_in[5];
    const float* cls_s  = (const float*)d_in[6];
    const float* cls_b  = (const float*)d_in[7];
    const float* cls_fw = (const float*)d_in[8];
    const float* cls_fb = (const float*)d_in[9];
    const float* reg_w  = (const float*)d_in[10];
    const float* reg_s  = (const float*)d_in[11];
    const float* reg_b  = (const float*)d_in[12];
    const float* reg_fw = (const float*)d_in[13];
    const float* reg_fb = (const float*)d_in[14];
    float* out = (float*)d_out;

    unsigned short *actC, *actA0, *actB0, *actA1, *actB1, *wc, *wr, *w1c;
    hipGetSymbolAddress((void**)&actC,  HIP_SYMBOL(g_actC));
    hipGetSymbolAddress((void**)&actA0, HIP_SYMBOL(g_actA0));
    hipGetSymbolAddress((void**)&actB0, HIP_SYMBOL(g_actB0));
    hipGetSymbolAddress((void**)&actA1, HIP_SYMBOL(g_actA1));
    hipGetSymbolAddress((void**)&actB1, HIP_SYMBOL(g_actB1));
    hipGetSymbolAddress((void**)&wc,    HIP_SYMBOL(g_wc));
    hipGetSymbolAddress((void**)&wr,    HIP_SYMBOL(g_wr));
    hipGetSymbolAddress((void**)&w1c,   HIP_SYMBOL(g_w1c));

    cvt_w3<<<dim3(256, 36, 2), 256, 0, stream>>>(cls_w, reg_w, wc, wr);
    cvt_w1<<<1, 256, 0, stream>>>(cls_fw, w1c);
    zero_halo<<<100, 256, 0, stream>>>(actC, actA0, actB0, actA1, actB1);
    cvt_in<<<dim3(256, 5, 4), 256, 0, stream>>>(
        (const float*)d_in[0], (const float*)d_in[1], (const float*)d_in[2],
        (const float*)d_in[3], (const float*)d_in[4], actC);

    unsigned short* srcs[4][2] = {{actC, actC}, {actA0, actA1}, {actB0, actB1}, {actA0, actA1}};
    unsigned short* dsts[4][2] = {{actA0, actA1}, {actB0, actB1}, {actA0, actA1}, {actB0, actB1}};
    for (int s = 0; s < 4; s++) {
        conv3x3_mfma<<<dim3(171, 1, 8), 512, 0, stream>>>(
            srcs[s][0], srcs[s][1], dsts[s][0], dsts[s][1],
            wc + (size_t)s * WSTEP, wr + (size_t)s * WSTEP,
            cls_s + s * 256, cls_b + s * 256, reg_s + s * 256, reg_b + s * 256);
    }

    final_cls<<<dim3(128, 5, 4), 256, 0, stream>>>(actB0, w1c, cls_fb, out);
    final_reg<<<dim3(64, 5, 4), 256, 0, stream>>>(actB1, reg_fw, reg_fb, out);
}